// Round 1
// baseline (306.805 us; speedup 1.0000x reference)
//
#include <hip/hip_runtime.h>
#include <hip/hip_bf16.h>
#include <math.h>

typedef float v4f __attribute__((ext_vector_type(4)));
typedef __bf16 bf16x8 __attribute__((ext_vector_type(8)));

#define NN   1024
#define INF  128
#define H0C  192
#define H1C  96

// ws byte offsets
#define WS_W0BF   0        // 24576 bf16 = 49152 B, B-fragment swizzled
#define WS_W1BF   49152    // 18432 bf16 = 36864 B
#define WS_BN0S   86016    // 192 f32
#define WS_BN0B   86784    // 192 f32
#define WS_BN1S   87552    // 96 f32
#define WS_BN1B   87936    // 96 f32
#define WS_WOUT   88320    // 96 f32
#define WS_CINV   88704    // 1024 f32 (column-sum reciprocal)

// ---------------------------------------------------------------------------
// Prep: swizzle weights into MFMA B-fragment order (bf16), fold BN.
// B-frag layout for mfma_f32_16x16x32_bf16: lane holds B[k=quad*8+j][n=lane&15]
// stored flat as [(ntile*KSTEPS+kstep)*64 + lane]*8 + j.
// ---------------------------------------------------------------------------
__global__ __launch_bounds__(256) void prep_kernel(
    const float* __restrict__ W0, const float* __restrict__ g0,
    const float* __restrict__ b0, const float* __restrict__ m0,
    const float* __restrict__ v0, const float* __restrict__ W1,
    const float* __restrict__ g1, const float* __restrict__ b1,
    const float* __restrict__ m1, const float* __restrict__ v1,
    const float* __restrict__ Wout, char* __restrict__ ws)
{
    int e = blockIdx.x * 256 + threadIdx.x;
    __bf16* w0bf = (__bf16*)(ws + WS_W0BF);
    __bf16* w1bf = (__bf16*)(ws + WS_W1BF);
    float* bn0s = (float*)(ws + WS_BN0S);
    float* bn0b = (float*)(ws + WS_BN0B);
    float* bn1s = (float*)(ws + WS_BN1S);
    float* bn1b = (float*)(ws + WS_BN1B);
    float* wout = (float*)(ws + WS_WOUT);
    if (e < 24576) {                       // W0: 12 ntiles x 4 ksteps
        int j = e & 7, lane = (e >> 3) & 63, t = e >> 9;
        int ks = t & 3, nt = t >> 2;
        int c = nt * 16 + (lane & 15);
        int k = ks * 32 + ((lane >> 4) << 3) + j;
        w0bf[e] = (__bf16)W0[c * INF + k];
    } else if (e < 43008) {                // W1: 6 ntiles x 6 ksteps
        int e2 = e - 24576;
        int j = e2 & 7, lane = (e2 >> 3) & 63, t = e2 >> 9;
        int ks = t % 6, nt = t / 6;
        int c = nt * 16 + (lane & 15);
        int k = ks * 32 + ((lane >> 4) << 3) + j;
        w1bf[e2] = (__bf16)W1[c * H0C + k];
    } else if (e < 43200) {                // BN0 fold
        int c = e - 43008;
        float s = g0[c] * rsqrtf(v0[c] + 1e-5f);
        bn0s[c] = s;
        bn0b[c] = b0[c] - m0[c] * s;
    } else if (e < 43296) {                // BN1 fold
        int c = e - 43200;
        float s = g1[c] * rsqrtf(v1[c] + 1e-5f);
        bn1s[c] = s;
        bn1b[c] = b1[c] - m1[c] * s;
    } else if (e < 43392) {                // Wout copy
        int c = e - 43296;
        wout[c] = Wout[c];
    }
}

// ---------------------------------------------------------------------------
// Main fused kernel: block = 16 i's x 8 j's = 128 pairs, 4 waves.
// X bf16 LDS [128][136] (pad 8 -> 2-way-only bank aliasing, free).
// H0 bf16 LDS [128][200] overlays X after barrier.
// ---------------------------------------------------------------------------
__global__ __launch_bounds__(256, 2) void edgenet_main(
    const float* __restrict__ feat, const char* __restrict__ ws,
    const float* __restrict__ boutp, float* __restrict__ sim_out)
{
    __shared__ __align__(16) char smem[51200];
    const int tid = threadIdx.x;
    const int lane = tid & 63;
    const int wave = tid >> 6;
    const int l16 = lane & 15;
    const int quad = lane >> 4;
    const int i0 = blockIdx.x << 4;
    const int j0 = blockIdx.y << 3;

    // ---- Phase 1: X[p][f] = |f_i - f_j| bf16 into LDS (stride 136 elems) ----
    #pragma unroll
    for (int it = 0; it < 8; ++it) {
        int c = it * 256 + tid;        // chunk id [0,2048): 16 chunks/row
        int p = c >> 4;                // pair row: p = jj*16 + ii
        int f0 = (c & 15) << 3;        // feature offset (8 per chunk)
        int ii = p & 15, jj = p >> 4;
        const float* fi = feat + (i0 + ii) * INF + f0;
        const float* fj = feat + (j0 + jj) * INF + f0;
        float4 a0 = *(const float4*)fi;
        float4 a1 = *(const float4*)(fi + 4);
        float4 q0 = *(const float4*)fj;
        float4 q1 = *(const float4*)(fj + 4);
        bf16x8 x;
        x[0] = (__bf16)fabsf(a0.x - q0.x);
        x[1] = (__bf16)fabsf(a0.y - q0.y);
        x[2] = (__bf16)fabsf(a0.z - q0.z);
        x[3] = (__bf16)fabsf(a0.w - q0.w);
        x[4] = (__bf16)fabsf(a1.x - q1.x);
        x[5] = (__bf16)fabsf(a1.y - q1.y);
        x[6] = (__bf16)fabsf(a1.z - q1.z);
        x[7] = (__bf16)fabsf(a1.w - q1.w);
        *(bf16x8*)(smem + p * 272 + f0 * 2) = x;
    }
    __syncthreads();

    // ---- Phase 2: load A-fragments (wave owns rows [mbase, mbase+32)) ----
    const int mbase = wave << 5;
    bf16x8 afrag[2][4];
    #pragma unroll
    for (int mt = 0; mt < 2; ++mt)
        #pragma unroll
        for (int ks = 0; ks < 4; ++ks)
            afrag[mt][ks] = *(const bf16x8*)(smem +
                (mbase + mt * 16 + l16) * 272 + ks * 64 + quad * 16);
    __syncthreads();   // all waves done reading X before H0 overwrites it

    // ---- Phase 3: GEMM1  H0 = X @ W0^T  (M=32/wave, K=128, N=192) ----
    const bf16x8* w0v = (const bf16x8*)(ws + WS_W0BF);
    v4f acc1[2][12];
    #pragma unroll
    for (int mt = 0; mt < 2; ++mt)
        #pragma unroll
        for (int nt = 0; nt < 12; ++nt)
            acc1[mt][nt] = (v4f){0.f, 0.f, 0.f, 0.f};
    #pragma unroll
    for (int nt = 0; nt < 12; ++nt) {
        #pragma unroll
        for (int ks = 0; ks < 4; ++ks) {
            bf16x8 b = w0v[(nt * 4 + ks) * 64 + lane];
            acc1[0][nt] = __builtin_amdgcn_mfma_f32_16x16x32_bf16(
                afrag[0][ks], b, acc1[0][nt], 0, 0, 0);
            acc1[1][nt] = __builtin_amdgcn_mfma_f32_16x16x32_bf16(
                afrag[1][ks], b, acc1[1][nt], 0, 0, 0);
        }
    }

    // ---- Phase 4: BN0 + leaky -> H0 bf16 LDS [128][200] (own rows only) ----
    const float* bn0s = (const float*)(ws + WS_BN0S);
    const float* bn0b = (const float*)(ws + WS_BN0B);
    #pragma unroll
    for (int nt = 0; nt < 12; ++nt) {
        int cch = nt * 16 + l16;
        float s = bn0s[cch], bb = bn0b[cch];
        #pragma unroll
        for (int mt = 0; mt < 2; ++mt)
            #pragma unroll
            for (int r = 0; r < 4; ++r) {
                float v = fmaf(acc1[mt][nt][r], s, bb);
                v = v >= 0.f ? v : 0.01f * v;
                int m = mbase + mt * 16 + quad * 4 + r;
                *(__bf16*)(smem + m * 400 + cch * 2) = (__bf16)v;
            }
    }
    __syncthreads();   // belt-and-braces (each wave reads only its own rows)

    // ---- Phase 5: GEMM2  H1 = H0 @ W1^T  (K=192, N=96) ----
    bf16x8 a2[2][6];
    #pragma unroll
    for (int mt = 0; mt < 2; ++mt)
        #pragma unroll
        for (int ks = 0; ks < 6; ++ks)
            a2[mt][ks] = *(const bf16x8*)(smem +
                (mbase + mt * 16 + l16) * 400 + ks * 64 + quad * 16);

    const bf16x8* w1v = (const bf16x8*)(ws + WS_W1BF);
    v4f acc2[2][6];
    #pragma unroll
    for (int mt = 0; mt < 2; ++mt)
        #pragma unroll
        for (int nt = 0; nt < 6; ++nt)
            acc2[mt][nt] = (v4f){0.f, 0.f, 0.f, 0.f};
    #pragma unroll
    for (int nt = 0; nt < 6; ++nt) {
        #pragma unroll
        for (int ks = 0; ks < 6; ++ks) {
            bf16x8 b = w1v[(nt * 6 + ks) * 64 + lane];
            acc2[0][nt] = __builtin_amdgcn_mfma_f32_16x16x32_bf16(
                a2[0][ks], b, acc2[0][nt], 0, 0, 0);
            acc2[1][nt] = __builtin_amdgcn_mfma_f32_16x16x32_bf16(
                a2[1][ks], b, acc2[1][nt], 0, 0, 0);
        }
    }

    // ---- Phase 6: BN1 + leaky + dot(Wout) + 16-lane reduce + sigmoid ----
    const float* bn1s = (const float*)(ws + WS_BN1S);
    const float* bn1b = (const float*)(ws + WS_BN1B);
    const float* wout = (const float*)(ws + WS_WOUT);
    float part[2][4] = {{0.f, 0.f, 0.f, 0.f}, {0.f, 0.f, 0.f, 0.f}};
    #pragma unroll
    for (int nt = 0; nt < 6; ++nt) {
        int cch = nt * 16 + l16;
        float s = bn1s[cch], bb = bn1b[cch], wo = wout[cch];
        #pragma unroll
        for (int mt = 0; mt < 2; ++mt)
            #pragma unroll
            for (int r = 0; r < 4; ++r) {
                float v = fmaf(acc2[mt][nt][r], s, bb);
                v = v >= 0.f ? v : 0.01f * v;
                part[mt][r] = fmaf(v, wo, part[mt][r]);
            }
    }
    #pragma unroll
    for (int off = 1; off < 16; off <<= 1) {
        #pragma unroll
        for (int mt = 0; mt < 2; ++mt)
            #pragma unroll
            for (int r = 0; r < 4; ++r)
                part[mt][r] += __shfl_xor(part[mt][r], off, 64);
    }
    if (l16 == 0) {
        float bout0 = boutp[0];
        #pragma unroll
        for (int mt = 0; mt < 2; ++mt)
            #pragma unroll
            for (int r = 0; r < 4; ++r) {
                int m = mbase + mt * 16 + quad * 4 + r;
                int ii = m & 15, jj = m >> 4;
                float logit = part[mt][r] + bout0;
                float sv = 1.f / (1.f + expf(-logit));
                sim_out[(i0 + ii) * NN + (j0 + jj)] = sv;
            }
    }
}

// ---------------------------------------------------------------------------
// Column sums over i: cinv[j] = 1 / (sum_i sim[i][j] + 1 + N*1e-6)
// ---------------------------------------------------------------------------
__global__ __launch_bounds__(256) void colsum_kernel(
    const float* __restrict__ sim, float* __restrict__ cinv)
{
    __shared__ float red[4][64];
    int jl = threadIdx.x & 63;
    int ig = threadIdx.x >> 6;
    int j = blockIdx.x * 64 + jl;
    float s = 0.f;
    for (int i = ig; i < NN; i += 4)
        s += sim[i * NN + j];
    red[ig][jl] = s;
    __syncthreads();
    if (ig == 0) {
        float t = red[0][jl] + red[1][jl] + red[2][jl] + red[3][jl];
        cinv[j] = 1.0f / (t + 1.0f + (float)NN * 1e-6f);
    }
}

// ---------------------------------------------------------------------------
// edge[i][j] = (sim + eye + 1e-6) * cinv[j]
// ---------------------------------------------------------------------------
__global__ __launch_bounds__(256) void edge_kernel(
    const float* __restrict__ sim, const float* __restrict__ cinv,
    float* __restrict__ edge)
{
    int gid = blockIdx.x * 256 + threadIdx.x;   // [0, 262144)
    int i = gid >> 8;
    int jc = (gid & 255) << 2;
    float4 s = *(const float4*)(sim + i * NN + jc);
    float4 w = *(const float4*)(cinv + jc);
    float4 o;
    o.x = (s.x + (i == jc + 0 ? 1.f : 0.f) + 1e-6f) * w.x;
    o.y = (s.y + (i == jc + 1 ? 1.f : 0.f) + 1e-6f) * w.y;
    o.z = (s.z + (i == jc + 2 ? 1.f : 0.f) + 1e-6f) * w.z;
    o.w = (s.w + (i == jc + 3 ? 1.f : 0.f) + 1e-6f) * w.w;
    *(float4*)(edge + i * NN + jc) = o;
}

extern "C" void kernel_launch(void* const* d_in, const int* in_sizes, int n_in,
                              void* d_out, int out_size, void* d_ws, size_t ws_size,
                              hipStream_t stream)
{
    const float* feat = (const float*)d_in[0];
    const float* W0   = (const float*)d_in[1];
    const float* g0   = (const float*)d_in[2];
    const float* b0   = (const float*)d_in[3];
    const float* m0   = (const float*)d_in[4];
    const float* v0   = (const float*)d_in[5];
    const float* W1   = (const float*)d_in[6];
    const float* g1   = (const float*)d_in[7];
    const float* b1   = (const float*)d_in[8];
    const float* m1   = (const float*)d_in[9];
    const float* v1   = (const float*)d_in[10];
    const float* Wout = (const float*)d_in[11];
    const float* bout = (const float*)d_in[12];
    char* ws = (char*)d_ws;
    float* edge = (float*)d_out;
    float* sim  = edge + NN * NN;
    float* cinv = (float*)(ws + WS_CINV);

    prep_kernel<<<dim3(170), dim3(256), 0, stream>>>(
        W0, g0, b0, m0, v0, W1, g1, b1, m1, v1, Wout, ws);
    edgenet_main<<<dim3(64, 128), dim3(256), 0, stream>>>(feat, ws, bout, sim);
    colsum_kernel<<<dim3(16), dim3(256), 0, stream>>>(sim, cinv);
    edge_kernel<<<dim3(1024), dim3(256), 0, stream>>>(sim, cinv, edge);
}

// Round 2
// 162.505 us; speedup vs baseline: 1.8880x; 1.8880x over previous
//
#include <hip/hip_runtime.h>
#include <hip/hip_bf16.h>
#include <math.h>

typedef float v4f __attribute__((ext_vector_type(4)));
typedef __bf16 bf16x8 __attribute__((ext_vector_type(8)));

#define NN   1024
#define INF  128
#define H0C  192
#define H1C  96

// ws byte offsets
#define WS_W0BF   0        // 24576 bf16 (BN0-scale folded), B-fragment swizzled
#define WS_W1BF   49152    // 18432 bf16 (BN1-scale folded)
#define WS_BN0B   86016    // 192 f32 folded bias
#define WS_BN1B   86784    // 96 f32 folded bias
#define WS_WOUT   87168    // 96 f32
#define WS_CINV   87552    // 1024 f32
#define WS_PART   91648    // 16*1024 f32 column partial sums

// ---------------------------------------------------------------------------
// Prep: swizzle weights into MFMA B-fragment order (bf16) with BN scale
// folded in; fold BN bias separately (added via accumulator init).
// B-frag layout for mfma_f32_16x16x32_bf16: lane holds B[k=quad*8+j][n=lane&15]
// stored flat as [(ntile*KSTEPS+kstep)*64 + lane]*8 + j.
// ---------------------------------------------------------------------------
__global__ __launch_bounds__(256) void prep_kernel(
    const float* __restrict__ W0, const float* __restrict__ g0,
    const float* __restrict__ b0, const float* __restrict__ m0,
    const float* __restrict__ v0, const float* __restrict__ W1,
    const float* __restrict__ g1, const float* __restrict__ b1,
    const float* __restrict__ m1, const float* __restrict__ v1,
    const float* __restrict__ Wout, char* __restrict__ ws)
{
    int e = blockIdx.x * 256 + threadIdx.x;
    __bf16* w0bf = (__bf16*)(ws + WS_W0BF);
    __bf16* w1bf = (__bf16*)(ws + WS_W1BF);
    float* bn0b = (float*)(ws + WS_BN0B);
    float* bn1b = (float*)(ws + WS_BN1B);
    float* wout = (float*)(ws + WS_WOUT);
    if (e < 24576) {                       // W0: 12 ntiles x 4 ksteps
        int j = e & 7, lane = (e >> 3) & 63, t = e >> 9;
        int ks = t & 3, nt = t >> 2;
        int c = nt * 16 + (lane & 15);
        int k = ks * 32 + ((lane >> 4) << 3) + j;
        float s = g0[c] * rsqrtf(v0[c] + 1e-5f);
        w0bf[e] = (__bf16)(W0[c * INF + k] * s);
    } else if (e < 43008) {                // W1: 6 ntiles x 6 ksteps
        int e2 = e - 24576;
        int j = e2 & 7, lane = (e2 >> 3) & 63, t = e2 >> 9;
        int ks = t % 6, nt = t / 6;
        int c = nt * 16 + (lane & 15);
        int k = ks * 32 + ((lane >> 4) << 3) + j;
        float s = g1[c] * rsqrtf(v1[c] + 1e-5f);
        w1bf[e2] = (__bf16)(W1[c * H0C + k] * s);
    } else if (e < 43200) {                // BN0 folded bias
        int c = e - 43008;
        float s = g0[c] * rsqrtf(v0[c] + 1e-5f);
        bn0b[c] = b0[c] - m0[c] * s;
    } else if (e < 43296) {                // BN1 folded bias
        int c = e - 43200;
        float s = g1[c] * rsqrtf(v1[c] + 1e-5f);
        bn1b[c] = b1[c] - m1[c] * s;
    } else if (e < 43392) {                // Wout copy
        int c = e - 43296;
        wout[c] = Wout[c];
    }
}

// ---------------------------------------------------------------------------
// Main fused kernel: block = 16 i's x 8 j's = 128 pairs, 4 waves.
// SYMMETRY: sim[i][j]==sim[j][i], so only tiles with bj >= 2*bi are launched
// (4160 of 8192); each writes both sim[i][j] and sim[j][i]. Overlapping
// diagonal tiles double-write identical values (benign).
// X bf16 LDS [128][136] elems; H0 bf16 LDS [128][200] overlays X.
// ---------------------------------------------------------------------------
__global__ __launch_bounds__(256, 2) void edgenet_main(
    const float* __restrict__ feat, const char* __restrict__ ws,
    const float* __restrict__ boutp, float* __restrict__ sim_out)
{
    __shared__ __align__(16) char smem[51200];
    const int tid = threadIdx.x;
    const int lane = tid & 63;
    const int wave = tid >> 6;
    const int l16 = lane & 15;
    const int quad = lane >> 4;

    // decode upper-triangular tile id -> (bi, bj): cum(bi) = bi*(129-bi)
    const int id = blockIdx.x;
    int bi = (int)((129.0f - sqrtf(16641.0f - 4.0f * (float)id)) * 0.5f);
    while (bi * (129 - bi) > id) --bi;
    while ((bi + 1) * (128 - bi) <= id) ++bi;
    const int bj = 2 * bi + (id - bi * (129 - bi));
    const int i0 = bi << 4;
    const int j0 = bj << 3;

    // ---- Phase 1: X[p][f] = |f_i - f_j| bf16 into LDS (stride 136 elems) ----
    #pragma unroll
    for (int it = 0; it < 8; ++it) {
        int c = it * 256 + tid;        // chunk id [0,2048): 16 chunks/row
        int p = c >> 4;                // pair row: p = jj*16 + ii
        int f0 = (c & 15) << 3;        // feature offset (8 per chunk)
        int ii = p & 15, jj = p >> 4;
        const float* fi = feat + (i0 + ii) * INF + f0;
        const float* fj = feat + (j0 + jj) * INF + f0;
        float4 a0 = *(const float4*)fi;
        float4 a1 = *(const float4*)(fi + 4);
        float4 q0 = *(const float4*)fj;
        float4 q1 = *(const float4*)(fj + 4);
        bf16x8 x;
        x[0] = (__bf16)fabsf(a0.x - q0.x);
        x[1] = (__bf16)fabsf(a0.y - q0.y);
        x[2] = (__bf16)fabsf(a0.z - q0.z);
        x[3] = (__bf16)fabsf(a0.w - q0.w);
        x[4] = (__bf16)fabsf(a1.x - q1.x);
        x[5] = (__bf16)fabsf(a1.y - q1.y);
        x[6] = (__bf16)fabsf(a1.z - q1.z);
        x[7] = (__bf16)fabsf(a1.w - q1.w);
        *(bf16x8*)(smem + p * 272 + f0 * 2) = x;
    }
    __syncthreads();

    // ---- Phase 2: load A-fragments (wave owns rows [mbase, mbase+32)) ----
    const int mbase = wave << 5;
    bf16x8 afrag[2][4];
    #pragma unroll
    for (int mt = 0; mt < 2; ++mt)
        #pragma unroll
        for (int ks = 0; ks < 4; ++ks)
            afrag[mt][ks] = *(const bf16x8*)(smem +
                (mbase + mt * 16 + l16) * 272 + ks * 64 + quad * 16);
    __syncthreads();   // all waves done reading X before H0 overwrites it

    // ---- Phase 3: GEMM1  H0 = X @ W0s^T + b0  (M=32/wave, K=128, N=192) ----
    const bf16x8* w0v = (const bf16x8*)(ws + WS_W0BF);
    const float* bn0b = (const float*)(ws + WS_BN0B);
    v4f acc1[2][12];
    #pragma unroll
    for (int nt = 0; nt < 12; ++nt) {
        float bb = bn0b[nt * 16 + l16];
        acc1[0][nt] = (v4f){bb, bb, bb, bb};
        acc1[1][nt] = acc1[0][nt];
    }
    #pragma unroll
    for (int nt = 0; nt < 12; ++nt) {
        #pragma unroll
        for (int ks = 0; ks < 4; ++ks) {
            bf16x8 b = w0v[(nt * 4 + ks) * 64 + lane];
            acc1[0][nt] = __builtin_amdgcn_mfma_f32_16x16x32_bf16(
                afrag[0][ks], b, acc1[0][nt], 0, 0, 0);
            acc1[1][nt] = __builtin_amdgcn_mfma_f32_16x16x32_bf16(
                afrag[1][ks], b, acc1[1][nt], 0, 0, 0);
        }
    }

    // ---- Phase 4: leaky -> H0 bf16 LDS [128][200] (own rows only) ----
    #pragma unroll
    for (int nt = 0; nt < 12; ++nt) {
        int cch = nt * 16 + l16;
        #pragma unroll
        for (int mt = 0; mt < 2; ++mt)
            #pragma unroll
            for (int r = 0; r < 4; ++r) {
                float v = acc1[mt][nt][r];
                v = fmaxf(v, 0.01f * v);
                int m = mbase + mt * 16 + quad * 4 + r;
                *(__bf16*)(smem + m * 400 + cch * 2) = (__bf16)v;
            }
    }
    __syncthreads();

    // ---- Phase 5: GEMM2  H1 = H0 @ W1s^T + b1  (K=192, N=96) ----
    bf16x8 a2[2][6];
    #pragma unroll
    for (int mt = 0; mt < 2; ++mt)
        #pragma unroll
        for (int ks = 0; ks < 6; ++ks)
            a2[mt][ks] = *(const bf16x8*)(smem +
                (mbase + mt * 16 + l16) * 400 + ks * 64 + quad * 16);

    const bf16x8* w1v = (const bf16x8*)(ws + WS_W1BF);
    const float* bn1b = (const float*)(ws + WS_BN1B);
    v4f acc2[2][6];
    #pragma unroll
    for (int nt = 0; nt < 6; ++nt) {
        float bb = bn1b[nt * 16 + l16];
        acc2[0][nt] = (v4f){bb, bb, bb, bb};
        acc2[1][nt] = acc2[0][nt];
    }
    #pragma unroll
    for (int nt = 0; nt < 6; ++nt) {
        #pragma unroll
        for (int ks = 0; ks < 6; ++ks) {
            bf16x8 b = w1v[(nt * 6 + ks) * 64 + lane];
            acc2[0][nt] = __builtin_amdgcn_mfma_f32_16x16x32_bf16(
                a2[0][ks], b, acc2[0][nt], 0, 0, 0);
            acc2[1][nt] = __builtin_amdgcn_mfma_f32_16x16x32_bf16(
                a2[1][ks], b, acc2[1][nt], 0, 0, 0);
        }
    }

    // ---- Phase 6: leaky + dot(Wout) + 16-lane reduce + sigmoid ----
    const float* wout = (const float*)(ws + WS_WOUT);
    float part[2][4] = {{0.f, 0.f, 0.f, 0.f}, {0.f, 0.f, 0.f, 0.f}};
    #pragma unroll
    for (int nt = 0; nt < 6; ++nt) {
        float wo = wout[nt * 16 + l16];
        #pragma unroll
        for (int mt = 0; mt < 2; ++mt)
            #pragma unroll
            for (int r = 0; r < 4; ++r) {
                float v = acc2[mt][nt][r];
                v = fmaxf(v, 0.01f * v);
                part[mt][r] = fmaf(v, wo, part[mt][r]);
            }
    }
    #pragma unroll
    for (int off = 1; off < 16; off <<= 1) {
        #pragma unroll
        for (int mt = 0; mt < 2; ++mt)
            #pragma unroll
            for (int r = 0; r < 4; ++r)
                part[mt][r] += __shfl_xor(part[mt][r], off, 64);
    }
    if (l16 == 0) {
        float bout0 = boutp[0];
        #pragma unroll
        for (int mt = 0; mt < 2; ++mt)
            #pragma unroll
            for (int r = 0; r < 4; ++r) {
                int m = mbase + mt * 16 + quad * 4 + r;
                int ii = m & 15, jj = m >> 4;
                float logit = part[mt][r] + bout0;
                float sv = 1.f / (1.f + expf(-logit));
                sim_out[(i0 + ii) * NN + (j0 + jj)] = sv;
                sim_out[(j0 + jj) * NN + (i0 + ii)] = sv;   // symmetric mirror
            }
    }
}

// ---------------------------------------------------------------------------
// Column partial sums: grid(16 jgroups, 16 igroups). part[ig][j] = sum over
// that igroup's 64 rows of sim[:, j].
// ---------------------------------------------------------------------------
__global__ __launch_bounds__(256) void colsum_kernel(
    const float* __restrict__ sim, float* __restrict__ part)
{
    __shared__ float red[4][64];
    int jl = threadIdx.x & 63;
    int ig = threadIdx.x >> 6;
    int j = blockIdx.x * 64 + jl;
    int ibase = blockIdx.y * 64 + ig * 16;
    float s = 0.f;
    #pragma unroll
    for (int r = 0; r < 16; ++r)
        s += sim[(ibase + r) * NN + j];
    red[ig][jl] = s;
    __syncthreads();
    if (ig == 0) {
        float t = red[0][jl] + red[1][jl] + red[2][jl] + red[3][jl];
        part[blockIdx.y * NN + j] = t;
    }
}

// ---------------------------------------------------------------------------
// Finalize: cinv[j] = 1 / (sum_p part[p][j] + 1 + N*1e-6)
// ---------------------------------------------------------------------------
__global__ __launch_bounds__(256) void finalize_kernel(
    const float* __restrict__ part, float* __restrict__ cinv)
{
    int j = blockIdx.x * 256 + threadIdx.x;
    float s = 0.f;
    #pragma unroll
    for (int p = 0; p < 16; ++p)
        s += part[p * NN + j];
    cinv[j] = 1.0f / (s + 1.0f + (float)NN * 1e-6f);
}

// ---------------------------------------------------------------------------
// edge[i][j] = (sim + eye + 1e-6) * cinv[j]
// ---------------------------------------------------------------------------
__global__ __launch_bounds__(256) void edge_kernel(
    const float* __restrict__ sim, const float* __restrict__ cinv,
    float* __restrict__ edge)
{
    int gid = blockIdx.x * 256 + threadIdx.x;   // [0, 262144)
    int i = gid >> 8;
    int jc = (gid & 255) << 2;
    float4 s = *(const float4*)(sim + i * NN + jc);
    float4 w = *(const float4*)(cinv + jc);
    float4 o;
    o.x = (s.x + (i == jc + 0 ? 1.f : 0.f) + 1e-6f) * w.x;
    o.y = (s.y + (i == jc + 1 ? 1.f : 0.f) + 1e-6f) * w.y;
    o.z = (s.z + (i == jc + 2 ? 1.f : 0.f) + 1e-6f) * w.z;
    o.w = (s.w + (i == jc + 3 ? 1.f : 0.f) + 1e-6f) * w.w;
    *(float4*)(edge + i * NN + jc) = o;
}

extern "C" void kernel_launch(void* const* d_in, const int* in_sizes, int n_in,
                              void* d_out, int out_size, void* d_ws, size_t ws_size,
                              hipStream_t stream)
{
    const float* feat = (const float*)d_in[0];
    const float* W0   = (const float*)d_in[1];
    const float* g0   = (const float*)d_in[2];
    const float* b0   = (const float*)d_in[3];
    const float* m0   = (const float*)d_in[4];
    const float* v0   = (const float*)d_in[5];
    const float* W1   = (const float*)d_in[6];
    const float* g1   = (const float*)d_in[7];
    const float* b1   = (const float*)d_in[8];
    const float* m1   = (const float*)d_in[9];
    const float* v1   = (const float*)d_in[10];
    const float* Wout = (const float*)d_in[11];
    const float* bout = (const float*)d_in[12];
    char* ws = (char*)d_ws;
    float* edge = (float*)d_out;
    float* sim  = edge + NN * NN;
    float* cinv = (float*)(ws + WS_CINV);
    float* part = (float*)(ws + WS_PART);

    prep_kernel<<<dim3(170), dim3(256), 0, stream>>>(
        W0, g0, b0, m0, v0, W1, g1, b1, m1, v1, Wout, ws);
    edgenet_main<<<dim3(4160), dim3(256), 0, stream>>>(feat, ws, bout, sim);
    colsum_kernel<<<dim3(16, 16), dim3(256), 0, stream>>>(sim, part);
    finalize_kernel<<<dim3(4), dim3(256), 0, stream>>>(part, cinv);
    edge_kernel<<<dim3(1024), dim3(256), 0, stream>>>(sim, cinv, edge);
}